// Round 2
// baseline (683.146 us; speedup 1.0000x reference)
//
#include <hip/hip_runtime.h>
#include <math.h>

// Problem constants (from reference)
#define NWAY   10
#define DIMD   64
#define HWN    49           // H*W = 7*7
#define NSUP   800          // N_WAY*K_SHOT*PRJ
#define NQRY   16000        // N_WAY*Q_QUERY*PRJ
#define NTRI   2080         // 64*65/2
#define FEAT_PER (DIMD*HWN) // 3136 floats per sample
#define KPAD   72           // bf16 row stride: 144 B/row -> 4-bank rotation,
                            // 16B-aligned fragment reads

typedef __attribute__((ext_vector_type(8))) short bf16x8;
typedef __attribute__((ext_vector_type(4))) float f32x4;

struct __align__(16) BDCShared {
    union {
        unsigned short hl[2*DIMD*KPAD];  // 18432 B: H[64][72], L[64][72]
        float part[256*12];              // 12288 B: reduction partials (query tail)
    } u;
    float dg[DIMD];
    float rm[DIMD];
    float w4[4];            // per-wave partial for tm
    float red[16];          // final 11 sums
};

// Map linear triu index k -> (i,j), j>=i, row-major triu of 64x64 (init only).
__device__ __forceinline__ void k2ij(int k, int& io, int& jo) {
    int ii = (int)floorf((129.0f - sqrtf(16641.0f - 8.0f*(float)k)) * 0.5f);
    int off = ii*(129-ii)/2;
    if (off > k) { --ii; off = ii*(129-ii)/2; }
    else {
        int off2 = (ii+1)*(128-ii)/2;
        if (off2 <= k) { ii += 1; off = off2; }
    }
    io = ii;
    jo = ii + (k - off);
}

// HW packed bf16 convert (RNE): r.lo16 = bf16(a), r.hi16 = bf16(b)
__device__ __forceinline__ unsigned cvt_pk_bf16(float a, float b) {
    unsigned r;
    asm("v_cvt_pk_bf16_f32 %0, %1, %2" : "=v"(r) : "v"(a), "v"(b));
    return r;
}

// MFMA-based BDC, fully register-resident output:
//   o[J][r]  = sqrt'd UNcentered dcov at (i = 16wv+4qd+r, j = 16J+c15)
//   rmi[r]   = row mean for i = 16wv+4qd+r (in-register)
//   sm.rm[j] = all 64 row means (LDS, for rm_j lookup)
//   returns tm (grand mean).
// No dcov matrix is ever written to LDS. Block = 256 threads = 4 waves.
__device__ __forceinline__ float bdc_compute(const float* __restrict__ feat,
                                             float et, int sample,
                                             BDCShared& sm, f32x4* o, f32x4& rmi) {
    const int tid = threadIdx.x;
    unsigned short* Hh = sm.u.hl;
    unsigned short* Lh = sm.u.hl + DIMD*KPAD;

    // ---- Stage: row-mapped. Thread owns (row d, quarter hq): 16 contiguous k.
    {
        const int d = tid & 63, hq = tid >> 6;       // hq is wave-uniform
        const float* rowp = feat + (size_t)sample * FEAT_PER + d*HWN + hq*16;
        float x[16];
        if (hq < 3) {
            #pragma unroll
            for (int i = 0; i < 16; ++i) x[i] = rowp[i];
        } else {
            x[0] = rowp[0];                          // k = 48
            #pragma unroll
            for (int i = 1; i < 16; ++i) x[i] = 0.0f;
        }
        unsigned hp[8], lp[8];
        #pragma unroll
        for (int i = 0; i < 8; ++i) {
            unsigned h = cvt_pk_bf16(x[2*i], x[2*i+1]);
            float h0 = __uint_as_float(h << 16);
            float h1 = __uint_as_float(h & 0xffff0000u);
            hp[i] = h;
            lp[i] = cvt_pk_bf16(x[2*i] - h0, x[2*i+1] - h1);
        }
        uint4* hd = (uint4*)&Hh[d*KPAD + hq*16];     // 144d+32hq B: 16B-aligned
        uint4* ld = (uint4*)&Lh[d*KPAD + hq*16];
        hd[0] = make_uint4(hp[0], hp[1], hp[2], hp[3]);
        hd[1] = make_uint4(hp[4], hp[5], hp[6], hp[7]);
        ld[0] = make_uint4(lp[0], lp[1], lp[2], lp[3]);
        ld[1] = make_uint4(lp[4], lp[5], lp[6], lp[7]);
    }
    __syncthreads();

    // ---- Gram via MFMA 16x16x32 bf16. Wave w owns G rows 16w..16w+15.
    const int wv = tid >> 6, lane = tid & 63;
    const int qd = lane >> 4, c15 = lane & 15;
    const int abase = (16*wv + c15)*KPAD + qd*8;
    bf16x8 AH0 = *(const bf16x8*)&Hh[abase];
    bf16x8 AH1 = *(const bf16x8*)&Hh[abase + 32];
    bf16x8 AL0 = *(const bf16x8*)&Lh[abase];
    bf16x8 AL1 = *(const bf16x8*)&Lh[abase + 32];

    f32x4 acc[4];
    #pragma unroll
    for (int J = 0; J < 4; ++J) {
        const int bbase = (16*J + c15)*KPAD + qd*8;
        bf16x8 BH0 = *(const bf16x8*)&Hh[bbase];
        bf16x8 BH1 = *(const bf16x8*)&Hh[bbase + 32];
        bf16x8 BL0 = *(const bf16x8*)&Lh[bbase];
        bf16x8 BL1 = *(const bf16x8*)&Lh[bbase + 32];
        f32x4 a = {0.f, 0.f, 0.f, 0.f};
        a = __builtin_amdgcn_mfma_f32_16x16x32_bf16(AH0, BH0, a, 0, 0, 0);
        a = __builtin_amdgcn_mfma_f32_16x16x32_bf16(AH1, BH1, a, 0, 0, 0);
        a = __builtin_amdgcn_mfma_f32_16x16x32_bf16(AL0, BH0, a, 0, 0, 0);
        a = __builtin_amdgcn_mfma_f32_16x16x32_bf16(AL1, BH1, a, 0, 0, 0);
        a = __builtin_amdgcn_mfma_f32_16x16x32_bf16(AH0, BL0, a, 0, 0, 0);
        a = __builtin_amdgcn_mfma_f32_16x16x32_bf16(AH1, BL1, a, 0, 0, 0);
        acc[J] = a;
    }

    // ---- dg from G diagonal (tile J == wv). C/D: col=lane&15, row=quad*4+reg.
    #pragma unroll
    for (int J = 0; J < 4; ++J) {
        if (J == wv) {
            #pragma unroll
            for (int r = 0; r < 4; ++r)
                if (c15 == 4*qd + r) sm.dg[16*wv + c15] = acc[J][r];
        }
    }
    __syncthreads();   // dg visible; all frag reads of u.hl done

    // ---- dcov in registers + in-register row sums
    f32x4 dgi = *(const f32x4*)&sm.dg[16*wv + 4*qd];
    float rs0 = 0.f, rs1 = 0.f, rs2 = 0.f, rs3 = 0.f;
    #pragma unroll
    for (int J = 0; J < 4; ++J) {
        float dgj = sm.dg[16*J + c15];
        #pragma unroll
        for (int r = 0; r < 4; ++r) {
            float t2 = fmaf(-2.0f, acc[J][r], dgi[r] + dgj);
            t2 = fmaxf(t2, 0.0f);
            o[J][r] = __builtin_amdgcn_sqrtf(fmaf(et, t2, 1e-5f));
        }
        rs0 += o[J][0]; rs1 += o[J][1]; rs2 += o[J][2]; rs3 += o[J][3];
    }
    // butterfly over the 16 c15-lanes: all lanes end with full row sums
    #pragma unroll
    for (int off = 1; off < 16; off <<= 1) {
        rs0 += __shfl_xor(rs0, off, 64);
        rs1 += __shfl_xor(rs1, off, 64);
        rs2 += __shfl_xor(rs2, off, 64);
        rs3 += __shfl_xor(rs3, off, 64);
    }
    if (c15 == 0) {
        f32x4 rmv = {rs0*(1.0f/64.0f), rs1*(1.0f/64.0f),
                     rs2*(1.0f/64.0f), rs3*(1.0f/64.0f)};
        *(f32x4*)&sm.rm[16*wv + 4*qd] = rmv;
    }
    float tt = (rs0 + rs1) + (rs2 + rs3);
    tt += __shfl_xor(tt, 16, 64);
    tt += __shfl_xor(tt, 32, 64);
    if (lane == 0) sm.w4[wv] = tt;
    __syncthreads();   // rm + w4 visible
    rmi[0] = rs0 * (1.0f/64.0f);
    rmi[1] = rs1 * (1.0f/64.0f);
    rmi[2] = rs2 * (1.0f/64.0f);
    rmi[3] = rs3 * (1.0f/64.0f);
    return (sm.w4[0] + sm.w4[1] + sm.w4[2] + sm.w4[3]) * (1.0f/4096.0f);
}

// init: build triu table ((i<<8)|j), zero s2 + loss slot
__global__ void kern_init(unsigned* __restrict__ table,
                          float* __restrict__ s2,
                          float* __restrict__ loss_slot) {
    int i = blockIdx.x * 256 + threadIdx.x;
    if (i < NTRI) {
        int ii, jj; k2ij(i, ii, jj);
        table[i] = ((unsigned)ii << 8) | (unsigned)jj;
    }
    if (i < NWAY) s2[i] = 0.0f;
    if (i == 0) loss_slot[0] = 0.0f;
}

// Support: BDC -> centered triu vector scattered to global from registers.
__global__ __launch_bounds__(256, 6) void kern_support(const float* __restrict__ feat,
                                                       const float* __restrict__ temp,
                                                       float* __restrict__ tvout) {
    __shared__ BDCShared sm;
    float et = __expf(temp[0]);
    int s = blockIdx.x;                 // 0..799
    f32x4 o[4]; f32x4 rmi;
    float tm = bdc_compute(feat, et, s, sm, o, rmi);

    const int tid = threadIdx.x;
    const int wv = tid >> 6, lane = tid & 63;
    const int qd = lane >> 4, c15 = lane & 15;
    const int iB = 16*wv + 4*qd;
    float* dst = tvout + (size_t)s * NTRI;
    #pragma unroll
    for (int J = 0; J < 4; ++J) {
        int j = 16*J + c15;
        float rmj = sm.rm[j];
        #pragma unroll
        for (int r = 0; r < 4; ++r) {
            int i = iB + r;
            if (j >= i) {
                float v = o[J][r] - rmi[r] - rmj + tm;
                dst[i*(129 - i)/2 + (j - i)] = v;
            }
        }
    }
}

// Deterministic reduce: prototype means -> FULL symmetric matrices Sfull[m][64][64]
// plus s2[m] = sum_triu S^2. Grid = NWAY * 9 blocks.
__global__ __launch_bounds__(256) void kern_reduce(const float* __restrict__ tv,
                                                   const unsigned* __restrict__ table,
                                                   float* __restrict__ Sfull,
                                                   float* __restrict__ s2) {
    __shared__ float red[4];
    int m = blockIdx.x / 9, kc = blockIdx.x % 9;
    int k = kc*256 + threadIdx.x;
    float ps = 0.0f;
    if (k < NTRI) {
        const float* p = tv + (size_t)(80*m) * NTRI + k;
        float a0 = 0.f, a1 = 0.f, a2 = 0.f, a3 = 0.f;
        for (int s4 = 0; s4 < 80; s4 += 4) {
            a0 += p[(size_t)(s4+0)*NTRI];
            a1 += p[(size_t)(s4+1)*NTRI];
            a2 += p[(size_t)(s4+2)*NTRI];
            a3 += p[(size_t)(s4+3)*NTRI];
        }
        float S = ((a0+a1)+(a2+a3)) * (1.0f/80.0f);
        unsigned t = table[k];
        int ii = (int)(t >> 8), jj = (int)(t & 255u);
        float* Sm = Sfull + (size_t)m * 4096;
        Sm[ii*64 + jj] = S;
        Sm[jj*64 + ii] = S;
        ps = S * S;
    }
    int lane = threadIdx.x & 63, wv = threadIdx.x >> 6;
    #pragma unroll
    for (int off = 32; off > 0; off >>= 1) ps += __shfl_xor(ps, off, 64);
    if (lane == 0) red[wv] = ps;
    __syncthreads();
    if (threadIdx.x == 0) atomicAdd(&s2[m], red[0]+red[1]+red[2]+red[3]);
}

// Query: BDC in registers -> weighted full-matrix dot products.
//   u = w*v (w = 0.5 off-diag, 1 on diag):
//   cross_triu[m] = sum_full u*S ;  qq_triu = 2*sum u^2 - u_diag^2
__global__ __launch_bounds__(256, 6) void kern_query(const float* __restrict__ feat,
                                                     const float* __restrict__ temp,
                                                     const float* __restrict__ Sfull,
                                                     const float* __restrict__ s2,
                                                     float* __restrict__ out) {
    __shared__ BDCShared sm;
    float et = __expf(temp[0]);
    int qn = blockIdx.x;                // 0..15999
    f32x4 o[4]; f32x4 rmi;
    float tm = bdc_compute(feat, et, NSUP + qn, sm, o, rmi);

    const int tid = threadIdx.x;
    const int wv = tid >> 6, lane = tid & 63;
    const int qd = lane >> 4, c15 = lane & 15;
    const int iB = 16*wv + 4*qd;

    // center + fold weight into u
    f32x4 u[4];
    #pragma unroll
    for (int J = 0; J < 4; ++J) {
        float rmj = sm.rm[16*J + c15];
        #pragma unroll
        for (int r = 0; r < 4; ++r) {
            float v = o[J][r] - rmi[r] - rmj + tm;
            u[J][r] = 0.5f * v;
        }
    }
    float dadj = 0.0f;
    if ((c15 >> 2) == qd) {             // this lane owns one diagonal element
        int r0 = c15 & 3;
        float ud = u[wv][r0] * 2.0f;    // restore full v on the diagonal
        u[wv][r0] = ud;
        dadj = ud * ud;
    }
    float qq2 = 0.0f;
    #pragma unroll
    for (int J = 0; J < 4; ++J) {
        #pragma unroll
        for (int r = 0; r < 4; ++r) qq2 = fmaf(u[J][r], u[J][r], qq2);
    }
    float qq = 2.0f*qq2 - dadj;

    float cr[NWAY];
    #pragma unroll
    for (int m = 0; m < NWAY; ++m) cr[m] = 0.0f;
    #pragma unroll
    for (int J = 0; J < 4; ++J) {
        const float* sp = Sfull + (16*J + c15)*64 + iB;
        f32x4 uj = u[J];
        #pragma unroll
        for (int m = 0; m < NWAY; ++m) {
            f32x4 sf = *(const f32x4*)(sp + (size_t)m*4096);
            cr[m] = fmaf(uj[0], sf[0], cr[m]);
            cr[m] = fmaf(uj[1], sf[1], cr[m]);
            cr[m] = fmaf(uj[2], sf[2], cr[m]);
            cr[m] = fmaf(uj[3], sf[3], cr[m]);
        }
    }

    // LDS transpose reduce: 3x b128 write/thread, 176 threads gather, 4-step shfl
    float* part = sm.u.part;            // safe: u.hl last read before dg barrier
    f32x4 p0 = {cr[0], cr[1], cr[2], cr[3]};
    f32x4 p1 = {cr[4], cr[5], cr[6], cr[7]};
    f32x4 p2 = {cr[8], cr[9], qq, 0.0f};
    *(f32x4*)&part[tid*12 + 0] = p0;
    *(f32x4*)&part[tid*12 + 4] = p1;
    *(f32x4*)&part[tid*12 + 8] = p2;
    __syncthreads();
    if (tid < 176) {
        int m = tid >> 4, g = tid & 15;
        float s = 0.0f;
        #pragma unroll
        for (int t = 0; t < 16; ++t) s += part[(g + 16*t)*12 + m];
        #pragma unroll
        for (int off = 1; off < 16; off <<= 1) s += __shfl_xor(s, off, 64);
        if (g == 0) sm.red[m] = s;
    }
    __syncthreads();
    if (tid < NWAY)
        out[(size_t)qn * NWAY + tid] = -(sm.red[10] + s2[tid] - 2.0f*sm.red[tid]);
}

// Softmax NLL partials: one atomicAdd per block.
__global__ __launch_bounds__(256) void kern_loss(const float* __restrict__ score,
                                                 const int* __restrict__ label,
                                                 float* __restrict__ loss_out) {
    __shared__ float red[4];
    int n = blockIdx.x * 256 + threadIdx.x;
    float lsum = 0.0f;
    if (n < NQRY) {
        const float* srow = score + (size_t)n * NWAY;
        float s[NWAY];
        float mx = -1e30f;
        #pragma unroll
        for (int m = 0; m < NWAY; ++m) { s[m] = srow[m]; mx = fmaxf(mx, s[m]); }
        float se = 0.0f;
        #pragma unroll
        for (int m = 0; m < NWAY; ++m) se += __expf(s[m] - mx);
        float lse = mx + __logf(se);
        lsum = lse - s[label[n]];
    }
    int lane = threadIdx.x & 63, wv = threadIdx.x >> 6;
    #pragma unroll
    for (int off = 32; off > 0; off >>= 1) lsum += __shfl_xor(lsum, off, 64);
    if (lane == 0) red[wv] = lsum;
    __syncthreads();
    if (threadIdx.x == 0)
        atomicAdd(loss_out, (red[0] + red[1] + red[2] + red[3]) * (1.0f / (float)NQRY));
}

extern "C" void kernel_launch(void* const* d_in, const int* in_sizes, int n_in,
                              void* d_out, int out_size, void* d_ws, size_t ws_size,
                              hipStream_t stream) {
    (void)in_sizes; (void)n_in; (void)out_size; (void)ws_size;
    const float* feat = (const float*)d_in[0];
    const float* temp = (const float*)d_in[1];
    const int*   label = (const int*)d_in[2];
    float* out = (float*)d_out;

    // workspace layout (~6.9 MB):
    float*    tv    = (float*)d_ws;                  // 800*2080 f = 6.656 MB
    float*    Sfull = tv + (size_t)NSUP * NTRI;      // 10*4096 f = 163.84 KB (16B-aligned)
    float*    s2    = Sfull + (size_t)NWAY * 4096;   // 10 f (+pad)
    unsigned* table = (unsigned*)(s2 + 16);          // 2080 u32
    float* loss_slot = out + (size_t)NQRY * NWAY;

    kern_init<<<(NTRI + 255)/256, 256, 0, stream>>>(table, s2, loss_slot);
    kern_support<<<NSUP, 256, 0, stream>>>(feat, temp, tv);
    kern_reduce<<<NWAY*9, 256, 0, stream>>>(tv, table, Sfull, s2);
    kern_query<<<NQRY, 256, 0, stream>>>(feat, temp, Sfull, s2, out);
    kern_loss<<<(NQRY + 255)/256, 256, 0, stream>>>(out, label, loss_slot);
}

// Round 3
// 668.346 us; speedup vs baseline: 1.0221x; 1.0221x over previous
//
#include <hip/hip_runtime.h>
#include <math.h>

// Problem constants (from reference)
#define NWAY   10
#define DIMD   64
#define HWN    49           // H*W = 7*7
#define NSUP   800          // N_WAY*K_SHOT*PRJ
#define NQRY   16000        // N_WAY*Q_QUERY*PRJ
#define NTRI   2080         // 64*65/2
#define FEAT_PER (DIMD*HWN) // 3136 floats per sample
#define KPAD   72           // bf16 row stride: 144 B/row -> 4-bank rotation,
                            // 16B-aligned fragment reads

typedef __attribute__((ext_vector_type(8))) short bf16x8;
typedef __attribute__((ext_vector_type(4))) float f32x4;

struct __align__(16) BDCShared {
    union {
        unsigned short hl[2*DIMD*KPAD];  // 18432 B: H[64][72], L[64][72]
        float part[256*12];              // 12288 B: reduction partials (query tail)
    } u;
    float dg[DIMD];
    float rm[DIMD];
    float w4[4];            // per-wave partial for tm
    float red[16];          // final 11 sums
};

// Map linear triu index k -> (i,j), j>=i, row-major triu of 64x64 (init only).
__device__ __forceinline__ void k2ij(int k, int& io, int& jo) {
    int ii = (int)floorf((129.0f - sqrtf(16641.0f - 8.0f*(float)k)) * 0.5f);
    int off = ii*(129-ii)/2;
    if (off > k) { --ii; off = ii*(129-ii)/2; }
    else {
        int off2 = (ii+1)*(128-ii)/2;
        if (off2 <= k) { ii += 1; off = off2; }
    }
    io = ii;
    jo = ii + (k - off);
}

// HW packed bf16 convert (RNE): r.lo16 = bf16(a), r.hi16 = bf16(b)
__device__ __forceinline__ unsigned cvt_pk_bf16(float a, float b) {
    unsigned r;
    asm("v_cvt_pk_bf16_f32 %0, %1, %2" : "=v"(r) : "v"(a), "v"(b));
    return r;
}

// MFMA-based BDC, fully register-resident output. NO arrays cross this
// boundary (scratch-spill safety, rule #20): outputs are named f32x4 refs.
//   oJ[r]  = sqrt'd UNcentered dcov at (i = 16wv+4qd+r, j = 16J+c15)
//   rmi[r] = row mean for i = 16wv+4qd+r; sm.rm[j] = all 64 row means (LDS)
//   returns tm (grand mean). Block = 256 threads = 4 waves.
__device__ __forceinline__ float bdc_compute(const float* __restrict__ feat,
                                             float et, int sample, BDCShared& sm,
                                             f32x4& o0, f32x4& o1, f32x4& o2,
                                             f32x4& o3, f32x4& rmi) {
    const int tid = threadIdx.x;
    unsigned short* Hh = sm.u.hl;
    unsigned short* Lh = sm.u.hl + DIMD*KPAD;

    // ---- Stage: row-mapped. Thread owns (row d, quarter hq): 16 contiguous k.
    {
        const int d = tid & 63, hq = tid >> 6;       // hq is wave-uniform
        const float* rowp = feat + (size_t)sample * FEAT_PER + d*HWN + hq*16;
        float x[16];
        if (hq < 3) {
            #pragma unroll
            for (int i = 0; i < 16; ++i) x[i] = rowp[i];
        } else {
            x[0] = rowp[0];                          // k = 48
            #pragma unroll
            for (int i = 1; i < 16; ++i) x[i] = 0.0f;
        }
        unsigned hp[8], lp[8];
        #pragma unroll
        for (int i = 0; i < 8; ++i) {
            unsigned h = cvt_pk_bf16(x[2*i], x[2*i+1]);
            float h0 = __uint_as_float(h << 16);
            float h1 = __uint_as_float(h & 0xffff0000u);
            hp[i] = h;
            lp[i] = cvt_pk_bf16(x[2*i] - h0, x[2*i+1] - h1);
        }
        uint4* hd = (uint4*)&Hh[d*KPAD + hq*16];     // 144d+32hq B: 16B-aligned
        uint4* ld = (uint4*)&Lh[d*KPAD + hq*16];
        hd[0] = make_uint4(hp[0], hp[1], hp[2], hp[3]);
        hd[1] = make_uint4(hp[4], hp[5], hp[6], hp[7]);
        ld[0] = make_uint4(lp[0], lp[1], lp[2], lp[3]);
        ld[1] = make_uint4(lp[4], lp[5], lp[6], lp[7]);
    }
    __syncthreads();

    // ---- Gram via MFMA 16x16x32 bf16. Wave w owns G rows 16w..16w+15.
    const int wv = tid >> 6, lane = tid & 63;
    const int qd = lane >> 4, c15 = lane & 15;
    const int abase = (16*wv + c15)*KPAD + qd*8;
    bf16x8 AH0 = *(const bf16x8*)&Hh[abase];
    bf16x8 AH1 = *(const bf16x8*)&Hh[abase + 32];
    bf16x8 AL0 = *(const bf16x8*)&Lh[abase];
    bf16x8 AL1 = *(const bf16x8*)&Lh[abase + 32];

    f32x4 acc[4];                      // constant-indexed only (unrolled)
    #pragma unroll
    for (int J = 0; J < 4; ++J) {
        const int bbase = (16*J + c15)*KPAD + qd*8;
        bf16x8 BH0 = *(const bf16x8*)&Hh[bbase];
        bf16x8 BH1 = *(const bf16x8*)&Hh[bbase + 32];
        bf16x8 BL0 = *(const bf16x8*)&Lh[bbase];
        bf16x8 BL1 = *(const bf16x8*)&Lh[bbase + 32];
        f32x4 a = {0.f, 0.f, 0.f, 0.f};
        a = __builtin_amdgcn_mfma_f32_16x16x32_bf16(AH0, BH0, a, 0, 0, 0);
        a = __builtin_amdgcn_mfma_f32_16x16x32_bf16(AH1, BH1, a, 0, 0, 0);
        a = __builtin_amdgcn_mfma_f32_16x16x32_bf16(AL0, BH0, a, 0, 0, 0);
        a = __builtin_amdgcn_mfma_f32_16x16x32_bf16(AL1, BH1, a, 0, 0, 0);
        a = __builtin_amdgcn_mfma_f32_16x16x32_bf16(AH0, BL0, a, 0, 0, 0);
        a = __builtin_amdgcn_mfma_f32_16x16x32_bf16(AH1, BL1, a, 0, 0, 0);
        acc[J] = a;
    }

    // ---- dg from G diagonal (tile J == wv). C/D: col=lane&15, row=quad*4+reg.
    #pragma unroll
    for (int J = 0; J < 4; ++J) {
        if (J == wv) {
            #pragma unroll
            for (int r = 0; r < 4; ++r)
                if (c15 == 4*qd + r) sm.dg[16*wv + c15] = acc[J][r];
        }
    }
    __syncthreads();   // dg visible; all frag reads of u.hl done

    // ---- dcov in registers (named o0..o3) + in-register row sums
    f32x4 dgi = *(const f32x4*)&sm.dg[16*wv + 4*qd];
    float rs0 = 0.f, rs1 = 0.f, rs2 = 0.f, rs3 = 0.f;
#define DCOV_J(J, OJ)                                                          \
    {   float dgj = sm.dg[16*(J) + c15];                                       \
        _Pragma("unroll")                                                      \
        for (int r = 0; r < 4; ++r) {                                          \
            float t2 = fmaf(-2.0f, acc[J][r], dgi[r] + dgj);                   \
            t2 = fmaxf(t2, 0.0f);                                              \
            OJ[r] = __builtin_amdgcn_sqrtf(fmaf(et, t2, 1e-5f));               \
        }                                                                      \
        rs0 += OJ[0]; rs1 += OJ[1]; rs2 += OJ[2]; rs3 += OJ[3]; }
    DCOV_J(0, o0)
    DCOV_J(1, o1)
    DCOV_J(2, o2)
    DCOV_J(3, o3)
#undef DCOV_J

    // butterfly over the 16 c15-lanes: all lanes end with full row sums
    #pragma unroll
    for (int off = 1; off < 16; off <<= 1) {
        rs0 += __shfl_xor(rs0, off, 64);
        rs1 += __shfl_xor(rs1, off, 64);
        rs2 += __shfl_xor(rs2, off, 64);
        rs3 += __shfl_xor(rs3, off, 64);
    }
    if (c15 == 0) {
        f32x4 rmv = {rs0*(1.0f/64.0f), rs1*(1.0f/64.0f),
                     rs2*(1.0f/64.0f), rs3*(1.0f/64.0f)};
        *(f32x4*)&sm.rm[16*wv + 4*qd] = rmv;
    }
    float tt = (rs0 + rs1) + (rs2 + rs3);
    tt += __shfl_xor(tt, 16, 64);
    tt += __shfl_xor(tt, 32, 64);
    if (lane == 0) sm.w4[wv] = tt;
    __syncthreads();   // rm + w4 visible
    rmi[0] = rs0 * (1.0f/64.0f);
    rmi[1] = rs1 * (1.0f/64.0f);
    rmi[2] = rs2 * (1.0f/64.0f);
    rmi[3] = rs3 * (1.0f/64.0f);
    return (sm.w4[0] + sm.w4[1] + sm.w4[2] + sm.w4[3]) * (1.0f/4096.0f);
}

// init: build triu table ((i<<8)|j), zero s2 + loss slot
__global__ void kern_init(unsigned* __restrict__ table,
                          float* __restrict__ s2,
                          float* __restrict__ loss_slot) {
    int i = blockIdx.x * 256 + threadIdx.x;
    if (i < NTRI) {
        int ii, jj; k2ij(i, ii, jj);
        table[i] = ((unsigned)ii << 8) | (unsigned)jj;
    }
    if (i < NWAY) s2[i] = 0.0f;
    if (i == 0) loss_slot[0] = 0.0f;
}

// Support: BDC -> centered triu vector scattered to global from registers.
__global__ __launch_bounds__(256, 6) void kern_support(const float* __restrict__ feat,
                                                       const float* __restrict__ temp,
                                                       float* __restrict__ tvout) {
    __shared__ BDCShared sm;
    float et = __expf(temp[0]);
    int s = blockIdx.x;                 // 0..799
    f32x4 o0, o1, o2, o3, rmi;
    float tm = bdc_compute(feat, et, s, sm, o0, o1, o2, o3, rmi);

    const int tid = threadIdx.x;
    const int wv = tid >> 6, lane = tid & 63;
    const int qd = lane >> 4, c15 = lane & 15;
    const int iB = 16*wv + 4*qd;
    float* dst = tvout + (size_t)s * NTRI;
#define SUP_J(J, OJ)                                                           \
    {   int j = 16*(J) + c15; float rmj = sm.rm[j];                            \
        _Pragma("unroll")                                                      \
        for (int r = 0; r < 4; ++r) {                                          \
            int i = iB + r;                                                    \
            if (j >= i)                                                        \
                dst[i*(129 - i)/2 + (j - i)] = OJ[r] - rmi[r] - rmj + tm; } }
    SUP_J(0, o0)
    SUP_J(1, o1)
    SUP_J(2, o2)
    SUP_J(3, o3)
#undef SUP_J
}

// Deterministic reduce: prototype means -> FULL symmetric matrices Sfull[m][64][64]
// plus s2[m] = sum_triu S^2. Grid = NWAY * 9 blocks.
__global__ __launch_bounds__(256) void kern_reduce(const float* __restrict__ tv,
                                                   const unsigned* __restrict__ table,
                                                   float* __restrict__ Sfull,
                                                   float* __restrict__ s2) {
    __shared__ float red[4];
    int m = blockIdx.x / 9, kc = blockIdx.x % 9;
    int k = kc*256 + threadIdx.x;
    float ps = 0.0f;
    if (k < NTRI) {
        const float* p = tv + (size_t)(80*m) * NTRI + k;
        float a0 = 0.f, a1 = 0.f, a2 = 0.f, a3 = 0.f;
        for (int s4 = 0; s4 < 80; s4 += 4) {
            a0 += p[(size_t)(s4+0)*NTRI];
            a1 += p[(size_t)(s4+1)*NTRI];
            a2 += p[(size_t)(s4+2)*NTRI];
            a3 += p[(size_t)(s4+3)*NTRI];
        }
        float S = ((a0+a1)+(a2+a3)) * (1.0f/80.0f);
        unsigned t = table[k];
        int ii = (int)(t >> 8), jj = (int)(t & 255u);
        float* Sm = Sfull + (size_t)m * 4096;
        Sm[ii*64 + jj] = S;
        Sm[jj*64 + ii] = S;
        ps = S * S;
    }
    int lane = threadIdx.x & 63, wv = threadIdx.x >> 6;
    #pragma unroll
    for (int off = 32; off > 0; off >>= 1) ps += __shfl_xor(ps, off, 64);
    if (lane == 0) red[wv] = ps;
    __syncthreads();
    if (threadIdx.x == 0) atomicAdd(&s2[m], red[0]+red[1]+red[2]+red[3]);
}

// Query: BDC in registers -> weighted full-matrix dot products.
//   u = w*v (w = 0.5 off-diag, 1 on diag):
//   cross_triu[m] = sum_full u*S ;  qq_triu = 2*sum u^2 - u_diag^2
__global__ __launch_bounds__(256, 6) void kern_query(const float* __restrict__ feat,
                                                     const float* __restrict__ temp,
                                                     const float* __restrict__ Sfull,
                                                     const float* __restrict__ s2,
                                                     float* __restrict__ out) {
    __shared__ BDCShared sm;
    float et = __expf(temp[0]);
    int qn = blockIdx.x;                // 0..15999
    f32x4 o0, o1, o2, o3, rmi;
    float tm = bdc_compute(feat, et, NSUP + qn, sm, o0, o1, o2, o3, rmi);

    const int tid = threadIdx.x;
    const int wv = tid >> 6, lane = tid & 63;
    const int qd = lane >> 4, c15 = lane & 15;
    const int iB = 16*wv + 4*qd;

    // center + fold weight into u (named vars; compile-time indexing ONLY)
    f32x4 u0, u1, u2, u3;
    float dadj = 0.0f;
#define CENTER_J(J, UJ, OJ)                                                    \
    {   float rmj = sm.rm[16*(J) + c15];                                       \
        _Pragma("unroll")                                                      \
        for (int r = 0; r < 4; ++r)                                            \
            UJ[r] = 0.5f * (OJ[r] - rmi[r] - rmj + tm);                        \
        if (wv == (J) && (c15 >> 2) == qd) {                                   \
            _Pragma("unroll")                                                  \
            for (int r = 0; r < 4; ++r)                                        \
                if ((c15 & 3) == r) {                                          \
                    UJ[r] *= 2.0f;           /* restore full v on diagonal */  \
                    dadj = UJ[r] * UJ[r];                                      \
                } } }
    CENTER_J(0, u0, o0)
    CENTER_J(1, u1, o1)
    CENTER_J(2, u2, o2)
    CENTER_J(3, u3, o3)
#undef CENTER_J

    float qq2 = 0.0f;
    #pragma unroll
    for (int r = 0; r < 4; ++r) {
        qq2 = fmaf(u0[r], u0[r], qq2);
        qq2 = fmaf(u1[r], u1[r], qq2);
        qq2 = fmaf(u2[r], u2[r], qq2);
        qq2 = fmaf(u3[r], u3[r], qq2);
    }
    float qq = 2.0f*qq2 - dadj;

    float cr[NWAY];                    // constant-indexed only (unrolled)
    #pragma unroll
    for (int m = 0; m < NWAY; ++m) cr[m] = 0.0f;
#define CROSS_J(J, UJ)                                                         \
    {   const float* sp = Sfull + (16*(J) + c15)*64 + iB;                      \
        _Pragma("unroll")                                                      \
        for (int m = 0; m < NWAY; ++m) {                                       \
            f32x4 sf = *(const f32x4*)(sp + (size_t)m*4096);                   \
            cr[m] = fmaf(UJ[0], sf[0], cr[m]);                                 \
            cr[m] = fmaf(UJ[1], sf[1], cr[m]);                                 \
            cr[m] = fmaf(UJ[2], sf[2], cr[m]);                                 \
            cr[m] = fmaf(UJ[3], sf[3], cr[m]); } }
    CROSS_J(0, u0)
    CROSS_J(1, u1)
    CROSS_J(2, u2)
    CROSS_J(3, u3)
#undef CROSS_J

    // LDS transpose reduce: 3x b128 write/thread, 176 threads gather, 4-step shfl
    float* part = sm.u.part;            // safe: u.hl last read before dg barrier
    f32x4 p0 = {cr[0], cr[1], cr[2], cr[3]};
    f32x4 p1 = {cr[4], cr[5], cr[6], cr[7]};
    f32x4 p2 = {cr[8], cr[9], qq, 0.0f};
    *(f32x4*)&part[tid*12 + 0] = p0;
    *(f32x4*)&part[tid*12 + 4] = p1;
    *(f32x4*)&part[tid*12 + 8] = p2;
    __syncthreads();
    if (tid < 176) {
        int m = tid >> 4, g = tid & 15;
        float s = 0.0f;
        #pragma unroll
        for (int t = 0; t < 16; ++t) s += part[(g + 16*t)*12 + m];
        #pragma unroll
        for (int off = 1; off < 16; off <<= 1) s += __shfl_xor(s, off, 64);
        if (g == 0) sm.red[m] = s;
    }
    __syncthreads();
    if (tid < NWAY)
        out[(size_t)qn * NWAY + tid] = -(sm.red[10] + s2[tid] - 2.0f*sm.red[tid]);
}

// Softmax NLL partials: one atomicAdd per block.
__global__ __launch_bounds__(256) void kern_loss(const float* __restrict__ score,
                                                 const int* __restrict__ label,
                                                 float* __restrict__ loss_out) {
    __shared__ float red[4];
    int n = blockIdx.x * 256 + threadIdx.x;
    float lsum = 0.0f;
    if (n < NQRY) {
        const float* srow = score + (size_t)n * NWAY;
        float s[NWAY];
        float mx = -1e30f;
        #pragma unroll
        for (int m = 0; m < NWAY; ++m) { s[m] = srow[m]; mx = fmaxf(mx, s[m]); }
        float se = 0.0f;
        #pragma unroll
        for (int m = 0; m < NWAY; ++m) se += __expf(s[m] - mx);
        float lse = mx + __logf(se);
        lsum = lse - s[label[n]];
    }
    int lane = threadIdx.x & 63, wv = threadIdx.x >> 6;
    #pragma unroll
    for (int off = 32; off > 0; off >>= 1) lsum += __shfl_xor(lsum, off, 64);
    if (lane == 0) red[wv] = lsum;
    __syncthreads();
    if (threadIdx.x == 0)
        atomicAdd(loss_out, (red[0] + red[1] + red[2] + red[3]) * (1.0f / (float)NQRY));
}

extern "C" void kernel_launch(void* const* d_in, const int* in_sizes, int n_in,
                              void* d_out, int out_size, void* d_ws, size_t ws_size,
                              hipStream_t stream) {
    (void)in_sizes; (void)n_in; (void)out_size; (void)ws_size;
    const float* feat = (const float*)d_in[0];
    const float* temp = (const float*)d_in[1];
    const int*   label = (const int*)d_in[2];
    float* out = (float*)d_out;

    // workspace layout (~6.9 MB):
    float*    tv    = (float*)d_ws;                  // 800*2080 f = 6.656 MB
    float*    Sfull = tv + (size_t)NSUP * NTRI;      // 10*4096 f = 163.84 KB (16B-aligned)
    float*    s2    = Sfull + (size_t)NWAY * 4096;   // 10 f (+pad)
    unsigned* table = (unsigned*)(s2 + 16);          // 2080 u32
    float* loss_slot = out + (size_t)NQRY * NWAY;

    kern_init<<<(NTRI + 255)/256, 256, 0, stream>>>(table, s2, loss_slot);
    kern_support<<<NSUP, 256, 0, stream>>>(feat, temp, tv);
    kern_reduce<<<NWAY*9, 256, 0, stream>>>(tv, table, Sfull, s2);
    kern_query<<<NQRY, 256, 0, stream>>>(feat, temp, Sfull, s2, out);
    kern_loss<<<(NQRY + 255)/256, 256, 0, stream>>>(out, label, loss_slot);
}

// Round 4
// 557.760 us; speedup vs baseline: 1.2248x; 1.1983x over previous
//
#include <hip/hip_runtime.h>
#include <math.h>

// Problem constants (from reference)
#define NWAY   10
#define DIMD   64
#define HWN    49           // H*W = 7*7
#define NSUP   800          // N_WAY*K_SHOT*PRJ
#define NQRY   16000        // N_WAY*Q_QUERY*PRJ
#define NTRI   2080         // 64*65/2
#define FEAT_PER (DIMD*HWN) // 3136 floats per sample
#define KPAD   72           // bf16 row stride: 144 B/row -> 4-bank rotation,
                            // 16B-aligned fragment reads

typedef __attribute__((ext_vector_type(8))) short bf16x8;
typedef __attribute__((ext_vector_type(4))) float f32x4;

struct __align__(16) BDCShared {
    union {
        unsigned short hl[2*DIMD*KPAD];  // 18432 B: H[64][72], L[64][72]
        float part[256*12];              // 12288 B: reduction partials (query tail)
    } u;
    float dg[DIMD];
    float rm[DIMD];
    float w4[4];            // per-wave partial for tm
    float red[16];          // final 11 sums
};

// Map linear triu index k -> (i,j), j>=i, row-major triu of 64x64 (init only).
__device__ __forceinline__ void k2ij(int k, int& io, int& jo) {
    int ii = (int)floorf((129.0f - sqrtf(16641.0f - 8.0f*(float)k)) * 0.5f);
    int off = ii*(129-ii)/2;
    if (off > k) { --ii; off = ii*(129-ii)/2; }
    else {
        int off2 = (ii+1)*(128-ii)/2;
        if (off2 <= k) { ii += 1; off = off2; }
    }
    io = ii;
    jo = ii + (k - off);
}

// HW packed bf16 convert (RNE): r.lo16 = bf16(a), r.hi16 = bf16(b)
__device__ __forceinline__ unsigned cvt_pk_bf16(float a, float b) {
    unsigned r;
    asm("v_cvt_pk_bf16_f32 %0, %1, %2" : "=v"(r) : "v"(a), "v"(b));
    return r;
}

// MFMA-based BDC, fully register-resident output. NO arrays cross this
// boundary (scratch-spill safety, rule #20): outputs are named f32x4 refs.
//   oJ[r]  = sqrt'd UNcentered dcov at (i = 16wv+4qd+r, j = 16J+c15)
//   rmi[r] = row mean for i = 16wv+4qd+r; sm.rm[j] = all 64 row means (LDS)
//   returns tm (grand mean). Block = 256 threads = 4 waves.
__device__ __forceinline__ float bdc_compute(const float* __restrict__ feat,
                                             float et, int sample, BDCShared& sm,
                                             f32x4& o0, f32x4& o1, f32x4& o2,
                                             f32x4& o3, f32x4& rmi) {
    const int tid = threadIdx.x;
    unsigned short* Hh = sm.u.hl;
    unsigned short* Lh = sm.u.hl + DIMD*KPAD;

    // ---- Stage: row-mapped. Thread owns (row d, quarter hq): 16 contiguous k.
    {
        const int d = tid & 63, hq = tid >> 6;       // hq is wave-uniform
        const float* rowp = feat + (size_t)sample * FEAT_PER + d*HWN + hq*16;
        float x[16];
        if (hq < 3) {
            #pragma unroll
            for (int i = 0; i < 16; ++i) x[i] = rowp[i];
        } else {
            x[0] = rowp[0];                          // k = 48
            #pragma unroll
            for (int i = 1; i < 16; ++i) x[i] = 0.0f;
        }
        unsigned hp[8], lp[8];
        #pragma unroll
        for (int i = 0; i < 8; ++i) {
            unsigned h = cvt_pk_bf16(x[2*i], x[2*i+1]);
            float h0 = __uint_as_float(h << 16);
            float h1 = __uint_as_float(h & 0xffff0000u);
            hp[i] = h;
            lp[i] = cvt_pk_bf16(x[2*i] - h0, x[2*i+1] - h1);
        }
        uint4* hd = (uint4*)&Hh[d*KPAD + hq*16];     // 144d+32hq B: 16B-aligned
        uint4* ld = (uint4*)&Lh[d*KPAD + hq*16];
        hd[0] = make_uint4(hp[0], hp[1], hp[2], hp[3]);
        hd[1] = make_uint4(hp[4], hp[5], hp[6], hp[7]);
        ld[0] = make_uint4(lp[0], lp[1], lp[2], lp[3]);
        ld[1] = make_uint4(lp[4], lp[5], lp[6], lp[7]);
    }
    __syncthreads();

    // ---- Gram via MFMA 16x16x32 bf16. Wave w owns G rows 16w..16w+15.
    const int wv = tid >> 6, lane = tid & 63;
    const int qd = lane >> 4, c15 = lane & 15;
    const int abase = (16*wv + c15)*KPAD + qd*8;
    bf16x8 AH0 = *(const bf16x8*)&Hh[abase];
    bf16x8 AH1 = *(const bf16x8*)&Hh[abase + 32];
    bf16x8 AL0 = *(const bf16x8*)&Lh[abase];
    bf16x8 AL1 = *(const bf16x8*)&Lh[abase + 32];

    f32x4 acc[4];                      // constant-indexed only (unrolled)
    #pragma unroll
    for (int J = 0; J < 4; ++J) {
        const int bbase = (16*J + c15)*KPAD + qd*8;
        bf16x8 BH0 = *(const bf16x8*)&Hh[bbase];
        bf16x8 BH1 = *(const bf16x8*)&Hh[bbase + 32];
        bf16x8 BL0 = *(const bf16x8*)&Lh[bbase];
        bf16x8 BL1 = *(const bf16x8*)&Lh[bbase + 32];
        f32x4 a = {0.f, 0.f, 0.f, 0.f};
        a = __builtin_amdgcn_mfma_f32_16x16x32_bf16(AH0, BH0, a, 0, 0, 0);
        a = __builtin_amdgcn_mfma_f32_16x16x32_bf16(AH1, BH1, a, 0, 0, 0);
        a = __builtin_amdgcn_mfma_f32_16x16x32_bf16(AL0, BH0, a, 0, 0, 0);
        a = __builtin_amdgcn_mfma_f32_16x16x32_bf16(AL1, BH1, a, 0, 0, 0);
        a = __builtin_amdgcn_mfma_f32_16x16x32_bf16(AH0, BL0, a, 0, 0, 0);
        a = __builtin_amdgcn_mfma_f32_16x16x32_bf16(AH1, BL1, a, 0, 0, 0);
        acc[J] = a;
    }

    // ---- dg from G diagonal (tile J == wv). C/D: col=lane&15, row=quad*4+reg.
    #pragma unroll
    for (int J = 0; J < 4; ++J) {
        if (J == wv) {
            #pragma unroll
            for (int r = 0; r < 4; ++r)
                if (c15 == 4*qd + r) sm.dg[16*wv + c15] = acc[J][r];
        }
    }
    __syncthreads();   // dg visible; all frag reads of u.hl done

    // ---- dcov in registers (named o0..o3) + in-register row sums
    f32x4 dgi = *(const f32x4*)&sm.dg[16*wv + 4*qd];
    float rs0 = 0.f, rs1 = 0.f, rs2 = 0.f, rs3 = 0.f;
#define DCOV_J(J, OJ)                                                          \
    {   float dgj = sm.dg[16*(J) + c15];                                       \
        _Pragma("unroll")                                                      \
        for (int r = 0; r < 4; ++r) {                                          \
            float t2 = fmaf(-2.0f, acc[J][r], dgi[r] + dgj);                   \
            t2 = fmaxf(t2, 0.0f);                                              \
            OJ[r] = __builtin_amdgcn_sqrtf(fmaf(et, t2, 1e-5f));               \
        }                                                                      \
        rs0 += OJ[0]; rs1 += OJ[1]; rs2 += OJ[2]; rs3 += OJ[3]; }
    DCOV_J(0, o0)
    DCOV_J(1, o1)
    DCOV_J(2, o2)
    DCOV_J(3, o3)
#undef DCOV_J

    // butterfly over the 16 c15-lanes: all lanes end with full row sums
    #pragma unroll
    for (int off = 1; off < 16; off <<= 1) {
        rs0 += __shfl_xor(rs0, off, 64);
        rs1 += __shfl_xor(rs1, off, 64);
        rs2 += __shfl_xor(rs2, off, 64);
        rs3 += __shfl_xor(rs3, off, 64);
    }
    if (c15 == 0) {
        f32x4 rmv = {rs0*(1.0f/64.0f), rs1*(1.0f/64.0f),
                     rs2*(1.0f/64.0f), rs3*(1.0f/64.0f)};
        *(f32x4*)&sm.rm[16*wv + 4*qd] = rmv;
    }
    float tt = (rs0 + rs1) + (rs2 + rs3);
    tt += __shfl_xor(tt, 16, 64);
    tt += __shfl_xor(tt, 32, 64);
    if (lane == 0) sm.w4[wv] = tt;
    __syncthreads();   // rm + w4 visible
    rmi[0] = rs0 * (1.0f/64.0f);
    rmi[1] = rs1 * (1.0f/64.0f);
    rmi[2] = rs2 * (1.0f/64.0f);
    rmi[3] = rs3 * (1.0f/64.0f);
    return (sm.w4[0] + sm.w4[1] + sm.w4[2] + sm.w4[3]) * (1.0f/4096.0f);
}

// init: build triu table ((i<<8)|j), zero s2 + loss slot
__global__ void kern_init(unsigned* __restrict__ table,
                          float* __restrict__ s2,
                          float* __restrict__ loss_slot) {
    int i = blockIdx.x * 256 + threadIdx.x;
    if (i < NTRI) {
        int ii, jj; k2ij(i, ii, jj);
        table[i] = ((unsigned)ii << 8) | (unsigned)jj;
    }
    if (i < NWAY) s2[i] = 0.0f;
    if (i == 0) loss_slot[0] = 0.0f;
}

// Support: BDC -> centered triu vector scattered to global from registers.
// launch_bounds(256,4): 128-VGPR budget -> NO scratch spill (the (256,6)
// 85-VGPR cap was spilling o/u to scratch: 593 MB WRITE_SIZE in r3).
__global__ __launch_bounds__(256, 4) void kern_support(const float* __restrict__ feat,
                                                       const float* __restrict__ temp,
                                                       float* __restrict__ tvout) {
    __shared__ BDCShared sm;
    float et = __expf(temp[0]);
    int s = blockIdx.x;                 // 0..799
    f32x4 o0, o1, o2, o3, rmi;
    float tm = bdc_compute(feat, et, s, sm, o0, o1, o2, o3, rmi);

    const int tid = threadIdx.x;
    const int wv = tid >> 6, lane = tid & 63;
    const int qd = lane >> 4, c15 = lane & 15;
    const int iB = 16*wv + 4*qd;
    float* dst = tvout + (size_t)s * NTRI;
#define SUP_J(J, OJ)                                                           \
    {   int j = 16*(J) + c15; float rmj = sm.rm[j];                            \
        _Pragma("unroll")                                                      \
        for (int r = 0; r < 4; ++r) {                                          \
            int i = iB + r;                                                    \
            if (j >= i)                                                        \
                dst[i*(129 - i)/2 + (j - i)] = OJ[r] - rmi[r] - rmj + tm; } }
    SUP_J(0, o0)
    SUP_J(1, o1)
    SUP_J(2, o2)
    SUP_J(3, o3)
#undef SUP_J
}

// Deterministic reduce: prototype means -> FULL symmetric matrices Sfull[m][64][64]
// plus s2[m] = sum_triu S^2. Grid = NWAY * 9 blocks.
__global__ __launch_bounds__(256) void kern_reduce(const float* __restrict__ tv,
                                                   const unsigned* __restrict__ table,
                                                   float* __restrict__ Sfull,
                                                   float* __restrict__ s2) {
    __shared__ float red[4];
    int m = blockIdx.x / 9, kc = blockIdx.x % 9;
    int k = kc*256 + threadIdx.x;
    float ps = 0.0f;
    if (k < NTRI) {
        const float* p = tv + (size_t)(80*m) * NTRI + k;
        float a0 = 0.f, a1 = 0.f, a2 = 0.f, a3 = 0.f;
        for (int s4 = 0; s4 < 80; s4 += 4) {
            a0 += p[(size_t)(s4+0)*NTRI];
            a1 += p[(size_t)(s4+1)*NTRI];
            a2 += p[(size_t)(s4+2)*NTRI];
            a3 += p[(size_t)(s4+3)*NTRI];
        }
        float S = ((a0+a1)+(a2+a3)) * (1.0f/80.0f);
        unsigned t = table[k];
        int ii = (int)(t >> 8), jj = (int)(t & 255u);
        float* Sm = Sfull + (size_t)m * 4096;
        Sm[ii*64 + jj] = S;
        Sm[jj*64 + ii] = S;
        ps = S * S;
    }
    int lane = threadIdx.x & 63, wv = threadIdx.x >> 6;
    #pragma unroll
    for (int off = 32; off > 0; off >>= 1) ps += __shfl_xor(ps, off, 64);
    if (lane == 0) red[wv] = ps;
    __syncthreads();
    if (threadIdx.x == 0) atomicAdd(&s2[m], red[0]+red[1]+red[2]+red[3]);
}

// Query: BDC in registers -> weighted full-matrix dot products.
//   u = w*v (w = 0.5 off-diag, 1 on diag):
//   cross_triu[m] = sum_full u*S ;  qq_triu = 2*sum u^2 - u_diag^2
__global__ __launch_bounds__(256, 4) void kern_query(const float* __restrict__ feat,
                                                     const float* __restrict__ temp,
                                                     const float* __restrict__ Sfull,
                                                     const float* __restrict__ s2,
                                                     float* __restrict__ out) {
    __shared__ BDCShared sm;
    float et = __expf(temp[0]);
    int qn = blockIdx.x;                // 0..15999
    f32x4 o0, o1, o2, o3, rmi;
    float tm = bdc_compute(feat, et, NSUP + qn, sm, o0, o1, o2, o3, rmi);

    const int tid = threadIdx.x;
    const int wv = tid >> 6, lane = tid & 63;
    const int qd = lane >> 4, c15 = lane & 15;
    const int iB = 16*wv + 4*qd;

    // center + fold weight into u (named vars; compile-time indexing ONLY)
    f32x4 u0, u1, u2, u3;
    float dadj = 0.0f;
#define CENTER_J(J, UJ, OJ)                                                    \
    {   float rmj = sm.rm[16*(J) + c15];                                       \
        _Pragma("unroll")                                                      \
        for (int r = 0; r < 4; ++r)                                            \
            UJ[r] = 0.5f * (OJ[r] - rmi[r] - rmj + tm);                        \
        if (wv == (J) && (c15 >> 2) == qd) {                                   \
            _Pragma("unroll")                                                  \
            for (int r = 0; r < 4; ++r)                                        \
                if ((c15 & 3) == r) {                                          \
                    UJ[r] *= 2.0f;           /* restore full v on diagonal */  \
                    dadj = UJ[r] * UJ[r];                                      \
                } } }
    CENTER_J(0, u0, o0)
    CENTER_J(1, u1, o1)
    CENTER_J(2, u2, o2)
    CENTER_J(3, u3, o3)
#undef CENTER_J

    float qq2 = 0.0f;
    #pragma unroll
    for (int r = 0; r < 4; ++r) {
        qq2 = fmaf(u0[r], u0[r], qq2);
        qq2 = fmaf(u1[r], u1[r], qq2);
        qq2 = fmaf(u2[r], u2[r], qq2);
        qq2 = fmaf(u3[r], u3[r], qq2);
    }
    float qq = 2.0f*qq2 - dadj;

    float cr[NWAY];                    // constant-indexed only (unrolled)
    #pragma unroll
    for (int m = 0; m < NWAY; ++m) cr[m] = 0.0f;
#define CROSS_J(J, UJ)                                                         \
    {   const float* sp = Sfull + (16*(J) + c15)*64 + iB;                      \
        _Pragma("unroll")                                                      \
        for (int m = 0; m < NWAY; ++m) {                                       \
            f32x4 sf = *(const f32x4*)(sp + (size_t)m*4096);                   \
            cr[m] = fmaf(UJ[0], sf[0], cr[m]);                                 \
            cr[m] = fmaf(UJ[1], sf[1], cr[m]);                                 \
            cr[m] = fmaf(UJ[2], sf[2], cr[m]);                                 \
            cr[m] = fmaf(UJ[3], sf[3], cr[m]); } }
    CROSS_J(0, u0)
    CROSS_J(1, u1)
    CROSS_J(2, u2)
    CROSS_J(3, u3)
#undef CROSS_J

    // LDS transpose reduce: 3x b128 write/thread, 176 threads gather, 4-step shfl
    float* part = sm.u.part;            // safe: u.hl last read before dg barrier
    f32x4 p0 = {cr[0], cr[1], cr[2], cr[3]};
    f32x4 p1 = {cr[4], cr[5], cr[6], cr[7]};
    f32x4 p2 = {cr[8], cr[9], qq, 0.0f};
    *(f32x4*)&part[tid*12 + 0] = p0;
    *(f32x4*)&part[tid*12 + 4] = p1;
    *(f32x4*)&part[tid*12 + 8] = p2;
    __syncthreads();
    if (tid < 176) {
        int m = tid >> 4, g = tid & 15;
        float s = 0.0f;
        #pragma unroll
        for (int t = 0; t < 16; ++t) s += part[(g + 16*t)*12 + m];
        #pragma unroll
        for (int off = 1; off < 16; off <<= 1) s += __shfl_xor(s, off, 64);
        if (g == 0) sm.red[m] = s;
    }
    __syncthreads();
    if (tid < NWAY)
        out[(size_t)qn * NWAY + tid] = -(sm.red[10] + s2[tid] - 2.0f*sm.red[tid]);
}

// Softmax NLL partials: one atomicAdd per block.
__global__ __launch_bounds__(256) void kern_loss(const float* __restrict__ score,
                                                 const int* __restrict__ label,
                                                 float* __restrict__ loss_out) {
    __shared__ float red[4];
    int n = blockIdx.x * 256 + threadIdx.x;
    float lsum = 0.0f;
    if (n < NQRY) {
        const float* srow = score + (size_t)n * NWAY;
        float s[NWAY];
        float mx = -1e30f;
        #pragma unroll
        for (int m = 0; m < NWAY; ++m) { s[m] = srow[m]; mx = fmaxf(mx, s[m]); }
        float se = 0.0f;
        #pragma unroll
        for (int m = 0; m < NWAY; ++m) se += __expf(s[m] - mx);
        float lse = mx + __logf(se);
        lsum = lse - s[label[n]];
    }
    int lane = threadIdx.x & 63, wv = threadIdx.x >> 6;
    #pragma unroll
    for (int off = 32; off > 0; off >>= 1) lsum += __shfl_xor(lsum, off, 64);
    if (lane == 0) red[wv] = lsum;
    __syncthreads();
    if (threadIdx.x == 0)
        atomicAdd(loss_out, (red[0] + red[1] + red[2] + red[3]) * (1.0f / (float)NQRY));
}

extern "C" void kernel_launch(void* const* d_in, const int* in_sizes, int n_in,
                              void* d_out, int out_size, void* d_ws, size_t ws_size,
                              hipStream_t stream) {
    (void)in_sizes; (void)n_in; (void)out_size; (void)ws_size;
    const float* feat = (const float*)d_in[0];
    const float* temp = (const float*)d_in[1];
    const int*   label = (const int*)d_in[2];
    float* out = (float*)d_out;

    // workspace layout (~6.9 MB):
    float*    tv    = (float*)d_ws;                  // 800*2080 f = 6.656 MB
    float*    Sfull = tv + (size_t)NSUP * NTRI;      // 10*4096 f = 163.84 KB (16B-aligned)
    float*    s2    = Sfull + (size_t)NWAY * 4096;   // 10 f (+pad)
    unsigned* table = (unsigned*)(s2 + 16);          // 2080 u32
    float* loss_slot = out + (size_t)NQRY * NWAY;

    kern_init<<<(NTRI + 255)/256, 256, 0, stream>>>(table, s2, loss_slot);
    kern_support<<<NSUP, 256, 0, stream>>>(feat, temp, tv);
    kern_reduce<<<NWAY*9, 256, 0, stream>>>(tv, table, Sfull, s2);
    kern_query<<<NQRY, 256, 0, stream>>>(feat, temp, Sfull, s2, out);
    kern_loss<<<(NQRY + 255)/256, 256, 0, stream>>>(out, label, loss_slot);
}

// Round 5
// 349.964 us; speedup vs baseline: 1.9520x; 1.5938x over previous
//
#include <hip/hip_runtime.h>
#include <math.h>

// Problem constants (from reference)
#define NWAY   10
#define DIMD   64
#define HWN    49           // H*W = 7*7
#define NSUP   800          // N_WAY*K_SHOT*PRJ
#define NQRY   16000        // N_WAY*Q_QUERY*PRJ
#define NTRI   2080         // 64*65/2
#define FEAT_PER (DIMD*HWN) // 3136 floats per sample
#define LDST   68           // fp32 dcov row stride (4-bank rotation, 16B-aligned)
#define KPAD   72           // bf16 row stride: 144 B/row -> 4-bank rotation
#define STP    12           // transposed support row stride (floats): 48 B

typedef __attribute__((ext_vector_type(8))) short bf16x8;
typedef __attribute__((ext_vector_type(4))) float f32x4;

// LDS: hl (staging) -> dcov (centered matrix, tail input) -> part (reduction)
// all overlaid; each transition is guarded by a __syncthreads().
struct __align__(16) BDCShared {
    union {
        unsigned short hl[2*DIMD*KPAD];  // 18432 B: H[64][72], L[64][72]
        float dcov[DIMD*LDST];           // 17408 B: CENTERED dcov matrix
        float part[256*12];              // 12288 B: reduction partials (query tail)
    } u;
    float dg[DIMD];
    float rm[DIMD];
    float w4[4];            // per-wave partial for tm
    float red[16];          // final 11 sums
};

// Map linear triu index k -> (i,j), j>=i, row-major triu of 64x64 (init only).
__device__ __forceinline__ void k2ij(int k, int& io, int& jo) {
    int ii = (int)floorf((129.0f - sqrtf(16641.0f - 8.0f*(float)k)) * 0.5f);
    int off = ii*(129-ii)/2;
    if (off > k) { --ii; off = ii*(129-ii)/2; }
    else {
        int off2 = (ii+1)*(128-ii)/2;
        if (off2 <= k) { ii += 1; off = off2; }
    }
    io = ii;
    jo = ii + (k - off);
}

// HW packed bf16 convert (RNE): r.lo16 = bf16(a), r.hi16 = bf16(b)
__device__ __forceinline__ unsigned cvt_pk_bf16(float a, float b) {
    unsigned r;
    asm("v_cvt_pk_bf16_f32 %0, %1, %2" : "=v"(r) : "v"(a), "v"(b));
    return r;
}

// MFMA-based BDC. On return:
//   sm.u.dcov holds the full CENTERED dcov matrix (symmetric, stride LDST)
//   vJ[r] = centered value at (i = 16wv+4qd+r, j = 16J+c15) (register copy)
//   returns tm. Block = 256 threads = 4 waves. Structure = round-1 kernel
//   (VGPR ~28, occ ~79%) + pre-centering (fewer tail LDS reads).
__device__ __forceinline__ float bdc_compute(const float* __restrict__ feat,
                                             float et, int sample, BDCShared& sm,
                                             f32x4& v0, f32x4& v1, f32x4& v2,
                                             f32x4& v3) {
    const int tid = threadIdx.x;
    unsigned short* Hh = sm.u.hl;
    unsigned short* Lh = sm.u.hl + DIMD*KPAD;

    // ---- Stage: row-mapped. Thread owns (row d, quarter hq): 16 contiguous k.
    {
        const int d = tid & 63, hq = tid >> 6;       // hq is wave-uniform
        const float* rowp = feat + (size_t)sample * FEAT_PER + d*HWN + hq*16;
        float x[16];
        if (hq < 3) {
            #pragma unroll
            for (int i = 0; i < 16; ++i) x[i] = rowp[i];
        } else {
            x[0] = rowp[0];                          // k = 48
            #pragma unroll
            for (int i = 1; i < 16; ++i) x[i] = 0.0f;
        }
        unsigned hp[8], lp[8];
        #pragma unroll
        for (int i = 0; i < 8; ++i) {
            unsigned h = cvt_pk_bf16(x[2*i], x[2*i+1]);
            float h0 = __uint_as_float(h << 16);
            float h1 = __uint_as_float(h & 0xffff0000u);
            hp[i] = h;
            lp[i] = cvt_pk_bf16(x[2*i] - h0, x[2*i+1] - h1);
        }
        uint4* hd = (uint4*)&Hh[d*KPAD + hq*16];     // 144d+32hq B: 16B-aligned
        uint4* ld = (uint4*)&Lh[d*KPAD + hq*16];
        hd[0] = make_uint4(hp[0], hp[1], hp[2], hp[3]);
        hd[1] = make_uint4(hp[4], hp[5], hp[6], hp[7]);
        ld[0] = make_uint4(lp[0], lp[1], lp[2], lp[3]);
        ld[1] = make_uint4(lp[4], lp[5], lp[6], lp[7]);
    }
    __syncthreads();

    // ---- Gram via MFMA 16x16x32 bf16. Wave w owns G rows 16w..16w+15.
    const int wv = tid >> 6, lane = tid & 63;
    const int qd = lane >> 4, c15 = lane & 15;
    const int abase = (16*wv + c15)*KPAD + qd*8;
    bf16x8 AH0 = *(const bf16x8*)&Hh[abase];
    bf16x8 AH1 = *(const bf16x8*)&Hh[abase + 32];
    bf16x8 AL0 = *(const bf16x8*)&Lh[abase];
    bf16x8 AL1 = *(const bf16x8*)&Lh[abase + 32];

    f32x4 acc[4];                      // constant-indexed only (unrolled)
    #pragma unroll
    for (int J = 0; J < 4; ++J) {
        const int bbase = (16*J + c15)*KPAD + qd*8;
        bf16x8 BH0 = *(const bf16x8*)&Hh[bbase];
        bf16x8 BH1 = *(const bf16x8*)&Hh[bbase + 32];
        bf16x8 BL0 = *(const bf16x8*)&Lh[bbase];
        bf16x8 BL1 = *(const bf16x8*)&Lh[bbase + 32];
        f32x4 a = {0.f, 0.f, 0.f, 0.f};
        a = __builtin_amdgcn_mfma_f32_16x16x32_bf16(AH0, BH0, a, 0, 0, 0);
        a = __builtin_amdgcn_mfma_f32_16x16x32_bf16(AH1, BH1, a, 0, 0, 0);
        a = __builtin_amdgcn_mfma_f32_16x16x32_bf16(AL0, BH0, a, 0, 0, 0);
        a = __builtin_amdgcn_mfma_f32_16x16x32_bf16(AL1, BH1, a, 0, 0, 0);
        a = __builtin_amdgcn_mfma_f32_16x16x32_bf16(AH0, BL0, a, 0, 0, 0);
        a = __builtin_amdgcn_mfma_f32_16x16x32_bf16(AH1, BL1, a, 0, 0, 0);
        acc[J] = a;
    }

    // ---- dg from G diagonal (tile J == wv). C/D: col=lane&15, row=quad*4+reg.
    #pragma unroll
    for (int J = 0; J < 4; ++J) {
        if (J == wv) {
            #pragma unroll
            for (int r = 0; r < 4; ++r)
                if (c15 == 4*qd + r) sm.dg[16*wv + c15] = acc[J][r];
        }
    }
    __syncthreads();   // dg visible; all frag reads of u.hl done

    // ---- sqrt'd dcov in registers (v0..v3, uncentered) + in-register row sums
    f32x4 dgi = *(const f32x4*)&sm.dg[16*wv + 4*qd];
    float rs0 = 0.f, rs1 = 0.f, rs2 = 0.f, rs3 = 0.f;
#define DCOV_J(J, VJ)                                                          \
    {   float dgj = sm.dg[16*(J) + c15];                                       \
        _Pragma("unroll")                                                      \
        for (int r = 0; r < 4; ++r) {                                          \
            float t2 = fmaf(-2.0f, acc[J][r], dgi[r] + dgj);                   \
            t2 = fmaxf(t2, 0.0f);                                              \
            VJ[r] = __builtin_amdgcn_sqrtf(fmaf(et, t2, 1e-5f));               \
        }                                                                      \
        rs0 += VJ[0]; rs1 += VJ[1]; rs2 += VJ[2]; rs3 += VJ[3]; }
    DCOV_J(0, v0)
    DCOV_J(1, v1)
    DCOV_J(2, v2)
    DCOV_J(3, v3)
#undef DCOV_J

    // butterfly over the 16 c15-lanes: all lanes end with full row sums
    #pragma unroll
    for (int off = 1; off < 16; off <<= 1) {
        rs0 += __shfl_xor(rs0, off, 64);
        rs1 += __shfl_xor(rs1, off, 64);
        rs2 += __shfl_xor(rs2, off, 64);
        rs3 += __shfl_xor(rs3, off, 64);
    }
    if (c15 == 0) {
        f32x4 rmv = {rs0*(1.0f/64.0f), rs1*(1.0f/64.0f),
                     rs2*(1.0f/64.0f), rs3*(1.0f/64.0f)};
        *(f32x4*)&sm.rm[16*wv + 4*qd] = rmv;
    }
    float tt = (rs0 + rs1) + (rs2 + rs3);
    tt += __shfl_xor(tt, 16, 64);
    tt += __shfl_xor(tt, 32, 64);
    if (lane == 0) sm.w4[wv] = tt;
    __syncthreads();   // rm + w4 visible
    float tm = (sm.w4[0] + sm.w4[1] + sm.w4[2] + sm.w4[3]) * (1.0f/4096.0f);

    // ---- center in registers, write CENTERED matrix to LDS (transposed b128;
    // valid by symmetry). Tail then reads v directly -- no rm re-reads.
    const float rmi0 = rs0*(1.0f/64.0f), rmi1 = rs1*(1.0f/64.0f),
                rmi2 = rs2*(1.0f/64.0f), rmi3 = rs3*(1.0f/64.0f);
    float* dcov = sm.u.dcov;
    const int iB = 16*wv + 4*qd;
#define CENTER_J(J, VJ)                                                        \
    {   float rmj = sm.rm[16*(J) + c15] - tm;                                  \
        VJ[0] = VJ[0] - rmi0 - rmj;                                            \
        VJ[1] = VJ[1] - rmi1 - rmj;                                            \
        VJ[2] = VJ[2] - rmi2 - rmj;                                            \
        VJ[3] = VJ[3] - rmi3 - rmj;                                            \
        *(f32x4*)&dcov[(16*(J) + c15)*LDST + iB] = VJ; }
    CENTER_J(0, v0)
    CENTER_J(1, v1)
    CENTER_J(2, v2)
    CENTER_J(3, v3)
#undef CENTER_J
    __syncthreads();   // centered dcov visible
    return tm;
}

// init: build triu table (addr<<16 | i<<8 | j), zero s2 + loss slot
__global__ void kern_init(unsigned* __restrict__ table,
                          float* __restrict__ s2,
                          float* __restrict__ loss_slot) {
    int i = blockIdx.x * 256 + threadIdx.x;
    if (i < NTRI) {
        int ii, jj; k2ij(i, ii, jj);
        table[i] = ((unsigned)(ii*LDST + jj) << 16) | ((unsigned)ii << 8) | (unsigned)jj;
    }
    if (i < NWAY) s2[i] = 0.0f;
    if (i == 0) loss_slot[0] = 0.0f;
}

// Support: BDC -> centered triu vector scattered to global from registers.
__global__ __launch_bounds__(256, 6) void kern_support(const float* __restrict__ feat,
                                                       const float* __restrict__ temp,
                                                       float* __restrict__ tvout) {
    __shared__ BDCShared sm;
    float et = __expf(temp[0]);
    int s = blockIdx.x;                 // 0..799
    f32x4 v0, v1, v2, v3;
    bdc_compute(feat, et, s, sm, v0, v1, v2, v3);

    const int tid = threadIdx.x;
    const int wv = tid >> 6, lane = tid & 63;
    const int qd = lane >> 4, c15 = lane & 15;
    const int iB = 16*wv + 4*qd;
    float* dst = tvout + (size_t)s * NTRI;
#define SUP_J(J, VJ)                                                           \
    {   int j = 16*(J) + c15;                                                  \
        _Pragma("unroll")                                                      \
        for (int r = 0; r < 4; ++r) {                                          \
            int i = iB + r;                                                    \
            if (j >= i) dst[i*(129 - i)/2 + (j - i)] = VJ[r]; } }
    SUP_J(0, v0)
    SUP_J(1, v1)
    SUP_J(2, v2)
    SUP_J(3, v3)
#undef SUP_J
}

// Deterministic reduce: prototype means (transposed [k][12]) + s2.
// Grid = NWAY * 9 blocks; block (m, kc) handles k in [kc*256, kc*256+256).
__global__ __launch_bounds__(256) void kern_reduce(const float* __restrict__ tv,
                                                   const unsigned* __restrict__ table,
                                                   float* __restrict__ supT,
                                                   float* __restrict__ s2) {
    __shared__ float red[4];
    int m = blockIdx.x / 9, kc = blockIdx.x % 9;
    int k = kc*256 + threadIdx.x;
    float S = 0.0f;
    if (k < NTRI) {
        const float* p = tv + (size_t)(80*m) * NTRI + k;
        float a0 = 0.f, a1 = 0.f, a2 = 0.f, a3 = 0.f;
        for (int s4 = 0; s4 < 80; s4 += 4) {
            a0 += p[(size_t)(s4+0)*NTRI];
            a1 += p[(size_t)(s4+1)*NTRI];
            a2 += p[(size_t)(s4+2)*NTRI];
            a3 += p[(size_t)(s4+3)*NTRI];
        }
        S = ((a0+a1)+(a2+a3)) * (1.0f/80.0f);
        supT[k*STP + m] = S;
    }
    float ps = S * S;   // 0 for k >= NTRI
    int lane = threadIdx.x & 63, wv = threadIdx.x >> 6;
    #pragma unroll
    for (int off = 32; off > 0; off >>= 1) ps += __shfl_xor(ps, off, 64);
    if (lane == 0) red[wv] = ps;
    __syncthreads();
    if (threadIdx.x == 0) atomicAdd(&s2[m], red[0]+red[1]+red[2]+red[3]);
}

// Query: BDC (centered, in LDS) -> triu-table loop -> transpose reduce.
__global__ __launch_bounds__(256, 6) void kern_query(const float* __restrict__ feat,
                                                     const float* __restrict__ temp,
                                                     const unsigned* __restrict__ table,
                                                     const float* __restrict__ supT,
                                                     const float* __restrict__ s2,
                                                     float* __restrict__ out) {
    __shared__ BDCShared sm;
    float et = __expf(temp[0]);
    int qn = blockIdx.x;                // 0..15999
    f32x4 v0, v1, v2, v3;
    bdc_compute(feat, et, NSUP + qn, sm, v0, v1, v2, v3);

    const int tid = threadIdx.x;
    float qq = 0.0f;
    float cr[NWAY];                    // constant-indexed only (unrolled)
    #pragma unroll
    for (int m = 0; m < NWAY; ++m) cr[m] = 0.0f;

    const float* dcov = sm.u.dcov;
    for (int k = tid; k < NTRI; k += 256) {
        unsigned t = table[k];
        float v = dcov[t >> 16];       // already centered
        qq = fmaf(v, v, qq);
        const float4* sp = (const float4*)(supT + (size_t)k * STP);
        float4 sa = sp[0], sb = sp[1], sc = sp[2];   // cols 10,11 pad
        cr[0] = fmaf(v, sa.x, cr[0]);
        cr[1] = fmaf(v, sa.y, cr[1]);
        cr[2] = fmaf(v, sa.z, cr[2]);
        cr[3] = fmaf(v, sa.w, cr[3]);
        cr[4] = fmaf(v, sb.x, cr[4]);
        cr[5] = fmaf(v, sb.y, cr[5]);
        cr[6] = fmaf(v, sb.z, cr[6]);
        cr[7] = fmaf(v, sb.w, cr[7]);
        cr[8] = fmaf(v, sc.x, cr[8]);
        cr[9] = fmaf(v, sc.y, cr[9]);
    }
    __syncthreads();                   // all dcov reads done -> part overlay safe

    // LDS transpose reduce: 3x b128 write/thread, 176 threads gather, 4-step shfl
    float* part = sm.u.part;
    f32x4 p0 = {cr[0], cr[1], cr[2], cr[3]};
    f32x4 p1 = {cr[4], cr[5], cr[6], cr[7]};
    f32x4 p2 = {cr[8], cr[9], qq, 0.0f};
    *(f32x4*)&part[tid*12 + 0] = p0;
    *(f32x4*)&part[tid*12 + 4] = p1;
    *(f32x4*)&part[tid*12 + 8] = p2;
    __syncthreads();
    if (tid < 176) {
        int m = tid >> 4, g = tid & 15;
        float s = 0.0f;
        #pragma unroll
        for (int t = 0; t < 16; ++t) s += part[(g + 16*t)*12 + m];
        #pragma unroll
        for (int off = 1; off < 16; off <<= 1) s += __shfl_xor(s, off, 64);
        if (g == 0) sm.red[m] = s;
    }
    __syncthreads();
    if (tid < NWAY)
        out[(size_t)qn * NWAY + tid] = -(sm.red[10] + s2[tid] - 2.0f*sm.red[tid]);
}

// Softmax NLL partials: one atomicAdd per block.
__global__ __launch_bounds__(256) void kern_loss(const float* __restrict__ score,
                                                 const int* __restrict__ label,
                                                 float* __restrict__ loss_out) {
    __shared__ float red[4];
    int n = blockIdx.x * 256 + threadIdx.x;
    float lsum = 0.0f;
    if (n < NQRY) {
        const float* srow = score + (size_t)n * NWAY;
        float s[NWAY];
        float mx = -1e30f;
        #pragma unroll
        for (int m = 0; m < NWAY; ++m) { s[m] = srow[m]; mx = fmaxf(mx, s[m]); }
        float se = 0.0f;
        #pragma unroll
        for (int m = 0; m < NWAY; ++m) se += __expf(s[m] - mx);
        float lse = mx + __logf(se);
        lsum = lse - s[label[n]];
    }
    int lane = threadIdx.x & 63, wv = threadIdx.x >> 6;
    #pragma unroll
    for (int off = 32; off > 0; off >>= 1) lsum += __shfl_xor(lsum, off, 64);
    if (lane == 0) red[wv] = lsum;
    __syncthreads();
    if (threadIdx.x == 0)
        atomicAdd(loss_out, (red[0] + red[1] + red[2] + red[3]) * (1.0f / (float)NQRY));
}

extern "C" void kernel_launch(void* const* d_in, const int* in_sizes, int n_in,
                              void* d_out, int out_size, void* d_ws, size_t ws_size,
                              hipStream_t stream) {
    (void)in_sizes; (void)n_in; (void)out_size; (void)ws_size;
    const float* feat = (const float*)d_in[0];
    const float* temp = (const float*)d_in[1];
    const int*   label = (const int*)d_in[2];
    float* out = (float*)d_out;

    // workspace layout (~6.8 MB):
    float*    tv    = (float*)d_ws;                  // 800*2080 f = 6.656 MB
    float*    supT  = tv + (size_t)NSUP * NTRI;      // 2080*12 f (transposed+pad)
    float*    s2    = supT + NTRI*STP;               // 10 f (+pad)
    unsigned* table = (unsigned*)(s2 + 16);          // 2080 u32
    float* loss_slot = out + (size_t)NQRY * NWAY;

    kern_init<<<(NTRI + 255)/256, 256, 0, stream>>>(table, s2, loss_slot);
    kern_support<<<NSUP, 256, 0, stream>>>(feat, temp, tv);
    kern_reduce<<<NWAY*9, 256, 0, stream>>>(tv, table, supT, s2);
    kern_query<<<NQRY, 256, 0, stream>>>(feat, temp, table, supT, s2, out);
    kern_loss<<<(NQRY + 255)/256, 256, 0, stream>>>(out, label, loss_slot);
}